// Round 2
// baseline (189.720 us; speedup 1.0000x reference)
//
#include <hip/hip_runtime.h>

#define D 32
#define RANGE 128        // nodes per range; R = ceil(n/RANGE) = 782
#define RMAX 800         // LDS counter capacity (>= R)
#define JC 512           // edge chunks == blockDim of consumers' segment loops
#define CHUNKMAX 3200    // LDS record capacity per sort block (chunk = 3126)
#define CAP 2304         // gather LDS record capacity per range (mean 2048, +5.7 sigma)

// ---- K0: zero the out-degree histogram (replaces hipMemsetAsync -- host-side
// stream memsets inside kernel_launch break the harness's graph capture). ----
__global__ __launch_bounds__(256) void zero_outdeg(int4* __restrict__ outdeg4, int n4) {
    int i = blockIdx.x * 256 + threadIdx.x;
    if (i < n4) outdeg4[i] = make_int4(0, 0, 0, 0);
}

// ---- K1: per-chunk LDS counting-sort of DST records by range; chunk-contiguous
// coalesced write-out; publishes metaD[r][j] = localStart<<16 | count (transposed
// so consumers read coalesced). Out-degrees via fire-and-forget global atomics
// in pass 2 (which loads src anyway) -- replaces the whole src record stream.
// dst rec = (s | dl<<17, ef_masked).
__global__ __launch_bounds__(512) void sort_chunks(
        const int* __restrict__ src, const int* __restrict__ dst,
        const float* __restrict__ ef,
        uint2* __restrict__ recs, unsigned* __restrict__ metaD,
        int* __restrict__ outdeg,
        int E, int R, int chunk) {
    __shared__ uint2 sd[CHUNKMAX];           // 25.6 KB sorted dst records
    __shared__ int cd[RMAX];                 // per-range counts
    __shared__ int curD[RMAX];               // scan / cursors
    int j = blockIdx.x, t = threadIdx.x;
    int e0 = j * chunk, e1 = min(E, e0 + chunk), cntE = e1 - e0;
    for (int i = t; i < RMAX; i += 512) cd[i] = 0;
    __syncthreads();
    // pass 1: count dst per-range (dst only -- src not read here anymore)
    for (int e = e0 + 2 * t; e < e1; e += 1024) {
        if (e + 1 < e1) {
            int2 d2 = *(const int2*)(dst + e);
            atomicAdd(&cd[d2.x >> 7], 1);
            atomicAdd(&cd[d2.y >> 7], 1);
        } else {
            atomicAdd(&cd[dst[e] >> 7], 1);
        }
    }
    __syncthreads();
    // Hillis-Steele inclusive scan (RMAX entries, 2 per thread) -> exclusive cursors
    {
        int i1 = t + 512;
        curD[t] = cd[t];
        if (i1 < RMAX) curD[i1] = cd[i1];
        __syncthreads();
        for (int off = 1; off < RMAX; off <<= 1) {
            int v0 = (t >= off) ? curD[t - off] : 0;
            int v1 = 0;
            if (i1 < RMAX && i1 >= off) v1 = curD[i1 - off];
            __syncthreads();
            curD[t] += v0;
            if (i1 < RMAX) curD[i1] += v1;
            __syncthreads();
        }
        curD[t] -= cd[t];
        if (i1 < RMAX) curD[i1] -= cd[i1];
        __syncthreads();
    }
    // pass 2: place into LDS sorted by range + global out-degree histogram
    for (int e = e0 + t; e < e1; e += 512) {
        int s = src[e], d = dst[e];
        float w = (s == d) ? 0.0f : ef[e];
        atomicAdd(&outdeg[s], 1);            // fire-and-forget, hides under sort
        int pos = atomicAdd(&curD[d >> 7], 1);
        sd[pos] = make_uint2((unsigned)s | ((unsigned)(d & (RANGE - 1)) << 17),
                             __float_as_uint(w));
    }
    __syncthreads();
    // coalesced chunk-contiguous write-out
    size_t baseE = (size_t)j * chunk;
    for (int i = t; i < cntE; i += 512) recs[baseE + i] = sd[i];
    // transposed meta [r][j]: 4B scatters here (L2 merges across the 16 blocks
    // per line) buy coalesced 2KB reads in the consumer
    for (int i = t; i < R; i += 512)
        metaD[(size_t)i * JC + j] =
            ((unsigned)(curD[i] - cd[i]) << 16) | (unsigned)cd[i];
}

// ---- K2: trivial coalesced pre-scaled bf16 convert from global out-degrees. ----
__device__ __forceinline__ unsigned short f2bf(float x) {
    unsigned u = __float_as_uint(x);
    u += 0x7FFFu + ((u >> 16) & 1u);
    return (unsigned short)(u >> 16);
}

__global__ __launch_bounds__(256) void srcnorm_convert(
        const int* __restrict__ outdeg, const float* __restrict__ feat,
        unsigned short* __restrict__ featb, int n) {
    int i = blockIdx.x * 256 + threadIdx.x;  // one float4 chunk per thread
    int total = n * 8;                       // 8 float4 chunks per row
    if (i >= total) return;
    int row = i >> 3;
    float sn = rsqrtf((float)max(outdeg[row], 1));
    float4 f = ((const float4*)feat)[i];
    ushort4 u;
    u.x = f2bf(f.x * sn); u.y = f2bf(f.y * sn);
    u.z = f2bf(f.z * sn); u.w = f2bf(f.w * sn);
    ((ushort4*)featb)[i] = u;
}

// ---- K3: per-range segment collect -> LDS node-sort -> register gather + output.
__global__ __launch_bounds__(512) void gather_kernel(
        const float* __restrict__ feat, const unsigned short* __restrict__ featb,
        const uint2* __restrict__ recs, const unsigned* __restrict__ metaD,
        float* __restrict__ out, int n, int R, int chunk) {
    __shared__ uint2 raw[CAP];           // 18 KB segment-appended records
    __shared__ uint2 srec[CAP];          // 18 KB node-sorted records
    __shared__ int segpre[JC + 1];       // 2 KB segment-count prefix
    __shared__ int indeg[RANGE];         // counts, then reused as sort cursors
    __shared__ int pre[RANGE + 1];
    int r = blockIdx.x, t = threadIdx.x;
    int base = r * RANGE, lim = min(n - base, RANGE);
    unsigned m = metaD[(size_t)r * JC + t];   // coalesced: transposed layout
    int st = m >> 16, c = m & 0xFFFFu;
    segpre[t + 1] = c;
    if (t == 0) segpre[0] = 0;
    if (t < RANGE) indeg[t] = 0;
    __syncthreads();
    // Hillis-Steele inclusive scan over 512 segment counts
    for (int off = 1; off < JC; off <<= 1) {
        int v = (t + 1 > off) ? segpre[t + 1 - off] : 0;
        __syncthreads();
        segpre[t + 1] += v;
        __syncthreads();
    }
    int total = segpre[JC];
    bool ovf = total > CAP;
    // collect my segment into raw + count in-degrees (single global segment read)
    const uint2* p = recs + (size_t)t * chunk + st;
    if (!ovf) {
        int dp = segpre[t];
        for (int k = 0; k < c; k++) {
            uint2 rec = p[k];
            raw[dp + k] = rec;
            atomicAdd(&indeg[rec.x >> 17], 1);
        }
    } else {
        for (int k = 0; k < c; k++) atomicAdd(&indeg[p[k].x >> 17], 1);
    }
    __syncthreads();
    // node-count prefix scan (RANGE = 128)
    if (t < RANGE) pre[t + 1] = indeg[t];
    if (t == 0) pre[0] = 0;
    __syncthreads();
    for (int off = 1; off < RANGE; off <<= 1) {
        int v = 0;
        if (t < RANGE) { int idx = t + 1; if (idx > off) v = pre[idx - off]; }
        __syncthreads();
        if (t < RANGE) pre[t + 1] += v;
        __syncthreads();
    }
    if (t < RANGE) indeg[t] = pre[t];   // reuse indeg as sort cursors
    __syncthreads();
    // sort raw -> srec by node
    if (!ovf) {
        for (int i = t; i < total; i += 512) {
            uint2 rec = raw[i];
            int dl = rec.x >> 17;
            int pos = atomicAdd(&indeg[dl], 1);
            srec[pos] = make_uint2(rec.x & 0x1FFFFu, rec.y);
        }
    }
    __syncthreads();
    // gather: 4 lanes per node, 16B bf16 chunks, 4x unrolled register accumulation
    int node = t >> 2;
    int cch = t & 3;
    if (node >= lim) return;
    int p0i = pre[node];
    int cnt = pre[node + 1] - p0i;
    float a0 = 0.f, a1 = 0.f, a2 = 0.f, a3 = 0.f, a4 = 0.f, a5 = 0.f, a6 = 0.f, a7 = 0.f;
    if (!ovf) {
        const uint2* sp = srec + p0i;
        int i = 0;
        for (; i + 4 <= cnt; i += 4) {
            uint2 q0 = sp[i], q1 = sp[i + 1], q2 = sp[i + 2], q3 = sp[i + 3];
            uint4 b0 = ((const uint4*)(featb + (size_t)q0.x * D))[cch];
            uint4 b1 = ((const uint4*)(featb + (size_t)q1.x * D))[cch];
            uint4 b2 = ((const uint4*)(featb + (size_t)q2.x * D))[cch];
            uint4 b3 = ((const uint4*)(featb + (size_t)q3.x * D))[cch];
            float w0 = __uint_as_float(q0.y), w1 = __uint_as_float(q1.y);
            float w2 = __uint_as_float(q2.y), w3 = __uint_as_float(q3.y);
            a0 += __uint_as_float(b0.x << 16) * w0 + __uint_as_float(b1.x << 16) * w1
                + __uint_as_float(b2.x << 16) * w2 + __uint_as_float(b3.x << 16) * w3;
            a1 += __uint_as_float(b0.x & 0xFFFF0000u) * w0 + __uint_as_float(b1.x & 0xFFFF0000u) * w1
                + __uint_as_float(b2.x & 0xFFFF0000u) * w2 + __uint_as_float(b3.x & 0xFFFF0000u) * w3;
            a2 += __uint_as_float(b0.y << 16) * w0 + __uint_as_float(b1.y << 16) * w1
                + __uint_as_float(b2.y << 16) * w2 + __uint_as_float(b3.y << 16) * w3;
            a3 += __uint_as_float(b0.y & 0xFFFF0000u) * w0 + __uint_as_float(b1.y & 0xFFFF0000u) * w1
                + __uint_as_float(b2.y & 0xFFFF0000u) * w2 + __uint_as_float(b3.y & 0xFFFF0000u) * w3;
            a4 += __uint_as_float(b0.z << 16) * w0 + __uint_as_float(b1.z << 16) * w1
                + __uint_as_float(b2.z << 16) * w2 + __uint_as_float(b3.z << 16) * w3;
            a5 += __uint_as_float(b0.z & 0xFFFF0000u) * w0 + __uint_as_float(b1.z & 0xFFFF0000u) * w1
                + __uint_as_float(b2.z & 0xFFFF0000u) * w2 + __uint_as_float(b3.z & 0xFFFF0000u) * w3;
            a6 += __uint_as_float(b0.w << 16) * w0 + __uint_as_float(b1.w << 16) * w1
                + __uint_as_float(b2.w << 16) * w2 + __uint_as_float(b3.w << 16) * w3;
            a7 += __uint_as_float(b0.w & 0xFFFF0000u) * w0 + __uint_as_float(b1.w & 0xFFFF0000u) * w1
                + __uint_as_float(b2.w & 0xFFFF0000u) * w2 + __uint_as_float(b3.w & 0xFFFF0000u) * w3;
        }
        for (; i < cnt; i++) {
            uint2 q = sp[i];
            uint4 b = ((const uint4*)(featb + (size_t)q.x * D))[cch];
            float w = __uint_as_float(q.y);
            a0 += __uint_as_float(b.x << 16) * w;
            a1 += __uint_as_float(b.x & 0xFFFF0000u) * w;
            a2 += __uint_as_float(b.y << 16) * w;
            a3 += __uint_as_float(b.y & 0xFFFF0000u) * w;
            a4 += __uint_as_float(b.z << 16) * w;
            a5 += __uint_as_float(b.z & 0xFFFF0000u) * w;
            a6 += __uint_as_float(b.w << 16) * w;
            a7 += __uint_as_float(b.w & 0xFFFF0000u) * w;
        }
    } else {
        // overflow fallback: direct scan of all segments (statistically never taken)
        for (int j = 0; j < JC; j++) {
            unsigned mm = metaD[(size_t)r * JC + j];
            const uint2* pp = recs + (size_t)j * chunk + (mm >> 16);
            int cc = mm & 0xFFFFu;
            for (int k = 0; k < cc; k++) {
                uint2 rec = pp[k];
                if ((int)(rec.x >> 17) == node) {
                    uint4 b = ((const uint4*)(featb + (size_t)(rec.x & 0x1FFFFu) * D))[cch];
                    float w = __uint_as_float(rec.y);
                    a0 += __uint_as_float(b.x << 16) * w;
                    a1 += __uint_as_float(b.x & 0xFFFF0000u) * w;
                    a2 += __uint_as_float(b.y << 16) * w;
                    a3 += __uint_as_float(b.y & 0xFFFF0000u) * w;
                    a4 += __uint_as_float(b.z << 16) * w;
                    a5 += __uint_as_float(b.z & 0xFFFF0000u) * w;
                    a6 += __uint_as_float(b.w << 16) * w;
                    a7 += __uint_as_float(b.w & 0xFFFF0000u) * w;
                }
            }
        }
    }
    float dn = rsqrtf((float)max(cnt, 1));
    const float4* fr = (const float4*)(feat + (size_t)(base + node) * D);
    float4 fA = fr[cch * 2];
    float4 fB = fr[cch * 2 + 1];
    float v = fabsf(fA.x - a0 * dn) + fabsf(fA.y - a1 * dn) +
              fabsf(fA.z - a2 * dn) + fabsf(fA.w - a3 * dn) +
              fabsf(fB.x - a4 * dn) + fabsf(fB.y - a5 * dn) +
              fabsf(fB.z - a6 * dn) + fabsf(fB.w - a7 * dn);
    v += __shfl_xor(v, 1, 4);
    v += __shfl_xor(v, 2, 4);
    if (cch == 0) out[base + node] = v;
}

extern "C" void kernel_launch(void* const* d_in, const int* in_sizes, int n_in,
                              void* d_out, int out_size, void* d_ws, size_t ws_size,
                              hipStream_t stream) {
    const float* feat   = (const float*)d_in[0];
    const float* e_feat = (const float*)d_in[1];
    const int*   src    = (const int*)d_in[2];
    const int*   dst    = (const int*)d_in[3];
    const int E = in_sizes[2];
    const int n = in_sizes[0] / D;
    float* out = (float*)d_out;

    const int R = (n + RANGE - 1) / RANGE;              // 782
    const int chunk = (((E + JC - 1) / JC) + 1) & ~1;   // 3126 (even, <= CHUNKMAX, < 65536)

    // ws layout (16B-aligned):
    //   recs[JC*chunk] uint2 | metaD[R*JC] uint | outdeg[n] int (16B-padded) | featb[n*D] ushort
    char* p = (char*)d_ws;
    uint2* recs     = (uint2*)p;    p += ((size_t)JC * chunk * 8 + 15) & ~(size_t)15;
    unsigned* metaD = (unsigned*)p; p += ((size_t)R * JC * 4 + 15) & ~(size_t)15;
    int* outdeg     = (int*)p;
    const int n4 = (n + 3) / 4;                          // int4 cells covering outdeg
    p += ((size_t)n4 * 16 + 15) & ~(size_t)15;
    unsigned short* featb = (unsigned short*)p;

    zero_outdeg<<<(n4 + 255) / 256, 256, 0, stream>>>((int4*)outdeg, n4);

    sort_chunks<<<JC, 512, 0, stream>>>(src, dst, e_feat, recs, metaD, outdeg,
                                        E, R, chunk);

    srcnorm_convert<<<(n * 8 + 255) / 256, 256, 0, stream>>>(outdeg, feat, featb, n);

    gather_kernel<<<R, 512, 0, stream>>>(feat, featb, recs, metaD, out, n, R, chunk);
}

// Round 3
// 145.535 us; speedup vs baseline: 1.3036x; 1.3036x over previous
//
#include <hip/hip_runtime.h>

#define D 32
#define RANGE 128        // nodes per range; R = ceil(n/RANGE) = 782
#define RMAX 800         // LDS counter capacity (>= R); scans cover 2*512 >= RMAX
#define JC 512           // dst edge chunks == blockDim of gather's segment loop
#define CHUNKMAX 3200    // LDS record capacity per dst sort block (chunk = 3126)
#define CAP 2304         // gather LDS record capacity per range (mean 2048, +5.7 sigma)
#define SJC 128          // src edge chunks (coarse: 12500 edges -> 64B/cell segments)
#define SCHUNKMAX 12800  // LDS id capacity per src sort block (50 KB)

// ---- K1s: coarse per-chunk LDS counting-sort of SRC ids by range.
// 128 chunks of ~12500 edges -> avg (chunk,range) cell = 16 ids = 64B, so the
// degree-count consumer reads line-granular segments instead of 4-16B scatter
// (the 35-40us cost that per-edge global atomics / fine segments both paid).
__global__ __launch_bounds__(512) void sort_src(
        const int* __restrict__ src,
        unsigned* __restrict__ srcs, unsigned* __restrict__ metaS,
        int E, int R, int chunkS) {
    __shared__ unsigned ids[SCHUNKMAX];      // 50 KB sorted src ids
    __shared__ int cs[RMAX];
    __shared__ int cur[RMAX];
    int j = blockIdx.x, t = threadIdx.x;
    int e0 = j * chunkS, e1 = min(E, e0 + chunkS), cntE = e1 - e0;
    for (int i = t; i < RMAX; i += 512) cs[i] = 0;
    __syncthreads();
    // pass 1: count per-range
    for (int e = e0 + 2 * t; e < e1; e += 1024) {
        if (e + 1 < e1) {
            int2 s2 = *(const int2*)(src + e);
            atomicAdd(&cs[s2.x >> 7], 1);
            atomicAdd(&cs[s2.y >> 7], 1);
        } else {
            atomicAdd(&cs[src[e] >> 7], 1);
        }
    }
    __syncthreads();
    // Hillis-Steele inclusive scan (RMAX entries, 2 per thread) -> exclusive cursors
    {
        int i1 = t + 512;
        cur[t] = cs[t];
        if (i1 < RMAX) cur[i1] = cs[i1];
        __syncthreads();
        for (int off = 1; off < RMAX; off <<= 1) {
            int v0 = (t >= off) ? cur[t - off] : 0;
            int v1 = 0;
            if (i1 < RMAX && i1 >= off) v1 = cur[i1 - off];
            __syncthreads();
            cur[t] += v0;
            if (i1 < RMAX) cur[i1] += v1;
            __syncthreads();
        }
        cur[t] -= cs[t];
        if (i1 < RMAX) cur[i1] -= cs[i1];
        __syncthreads();
    }
    // pass 2: place sorted by range
    for (int e = e0 + t; e < e1; e += 512) {
        unsigned s = (unsigned)src[e];
        int pos = atomicAdd(&cur[s >> 7], 1);
        ids[pos] = s;
    }
    __syncthreads();
    // coalesced chunk-contiguous write-out
    size_t baseE = (size_t)j * chunkS;
    for (int i = t; i < cntE; i += 512) srcs[baseE + i] = ids[i];
    // meta coalesced [j][r] (consumer only does 128 strided 4B loads per block)
    // start,count <= 12800 -> both fit 16 bits; cur == start+count after pass 2
    for (int i = t; i < R; i += 512)
        metaS[(size_t)j * R + i] =
            ((unsigned)(cur[i] - cs[i]) << 16) | (unsigned)cs[i];
}

// ---- K1: per-chunk LDS counting-sort of DST records by range (atomic-free);
// chunk-contiguous coalesced write-out; metaD[r][j] transposed for coalesced
// consumer reads. dst rec = (s | dl<<17, ef_masked).
__global__ __launch_bounds__(512) void sort_chunks(
        const int* __restrict__ src, const int* __restrict__ dst,
        const float* __restrict__ ef,
        uint2* __restrict__ recs, unsigned* __restrict__ metaD,
        int E, int R, int chunk) {
    __shared__ uint2 sd[CHUNKMAX];           // 25.6 KB sorted dst records
    __shared__ int cd[RMAX];                 // per-range counts
    __shared__ int curD[RMAX];               // scan / cursors
    int j = blockIdx.x, t = threadIdx.x;
    int e0 = j * chunk, e1 = min(E, e0 + chunk), cntE = e1 - e0;
    for (int i = t; i < RMAX; i += 512) cd[i] = 0;
    __syncthreads();
    // pass 1: count dst per-range (dst only)
    for (int e = e0 + 2 * t; e < e1; e += 1024) {
        if (e + 1 < e1) {
            int2 d2 = *(const int2*)(dst + e);
            atomicAdd(&cd[d2.x >> 7], 1);
            atomicAdd(&cd[d2.y >> 7], 1);
        } else {
            atomicAdd(&cd[dst[e] >> 7], 1);
        }
    }
    __syncthreads();
    // Hillis-Steele inclusive scan -> exclusive cursors
    {
        int i1 = t + 512;
        curD[t] = cd[t];
        if (i1 < RMAX) curD[i1] = cd[i1];
        __syncthreads();
        for (int off = 1; off < RMAX; off <<= 1) {
            int v0 = (t >= off) ? curD[t - off] : 0;
            int v1 = 0;
            if (i1 < RMAX && i1 >= off) v1 = curD[i1 - off];
            __syncthreads();
            curD[t] += v0;
            if (i1 < RMAX) curD[i1] += v1;
            __syncthreads();
        }
        curD[t] -= cd[t];
        if (i1 < RMAX) curD[i1] -= cd[i1];
        __syncthreads();
    }
    // pass 2: place into LDS sorted by range (no global atomics)
    for (int e = e0 + t; e < e1; e += 512) {
        int s = src[e], d = dst[e];
        float w = (s == d) ? 0.0f : ef[e];
        int pos = atomicAdd(&curD[d >> 7], 1);
        sd[pos] = make_uint2((unsigned)s | ((unsigned)(d & (RANGE - 1)) << 17),
                             __float_as_uint(w));
    }
    __syncthreads();
    // coalesced chunk-contiguous write-out
    size_t baseE = (size_t)j * chunk;
    for (int i = t; i < cntE; i += 512) recs[baseE + i] = sd[i];
    // transposed meta [r][j]: 4B scatters here buy coalesced 2KB reads in gather
    for (int i = t; i < R; i += 512)
        metaD[(size_t)i * JC + j] =
            ((unsigned)(curD[i] - cd[i]) << 16) | (unsigned)cd[i];
}

// ---- K2: per-range out-degree count from coarse src segments + pre-scaled
// bf16 convert. Segments are ~64B line-granular; 4 threads per segment. ----
__device__ __forceinline__ unsigned short f2bf(float x) {
    unsigned u = __float_as_uint(x);
    u += 0x7FFFu + ((u >> 16) & 1u);
    return (unsigned short)(u >> 16);
}

__global__ __launch_bounds__(512) void srcnorm_convert(
        const unsigned* __restrict__ srcs, const unsigned* __restrict__ metaS,
        const float* __restrict__ feat, unsigned short* __restrict__ featb,
        int n, int R, int chunkS) {
    __shared__ int cnt[RANGE];
    __shared__ unsigned meta[SJC];
    int r = blockIdx.x, t = threadIdx.x;
    int base = r * RANGE, lim = min(n - base, RANGE);
    if (t < RANGE) cnt[t] = 0;
    if (t < SJC) meta[t] = metaS[(size_t)t * R + r];
    __syncthreads();
    // 4 threads per segment, consecutive ids within a segment
    int seg = t >> 2, sub = t & 3;
    {
        unsigned m = meta[seg];
        int st = m >> 16, c = m & 0xFFFFu;
        const unsigned* p = srcs + (size_t)seg * chunkS + st;
        for (int k = sub; k < c; k += 4)
            atomicAdd(&cnt[p[k] - (unsigned)base], 1);
    }
    __syncthreads();
    int total4 = lim * 8;   // 8 float4 chunks per row
    for (int i = t; i < total4; i += 512) {
        int row = i >> 3;
        float sn = rsqrtf((float)max(cnt[row], 1));
        float4 f = ((const float4*)(feat + (size_t)(base + row) * D))[i & 7];
        ushort4 u;
        u.x = f2bf(f.x * sn); u.y = f2bf(f.y * sn);
        u.z = f2bf(f.z * sn); u.w = f2bf(f.w * sn);
        ((ushort4*)(featb + (size_t)(base + row) * D))[i & 7] = u;
    }
}

// ---- K3: per-range segment collect -> LDS node-sort -> register gather + output.
__global__ __launch_bounds__(512) void gather_kernel(
        const float* __restrict__ feat, const unsigned short* __restrict__ featb,
        const uint2* __restrict__ recs, const unsigned* __restrict__ metaD,
        float* __restrict__ out, int n, int R, int chunk) {
    __shared__ uint2 raw[CAP];           // 18 KB segment-appended records
    __shared__ uint2 srec[CAP];          // 18 KB node-sorted records
    __shared__ int segpre[JC + 1];       // 2 KB segment-count prefix
    __shared__ int indeg[RANGE];         // counts, then reused as sort cursors
    __shared__ int pre[RANGE + 1];
    int r = blockIdx.x, t = threadIdx.x;
    int base = r * RANGE, lim = min(n - base, RANGE);
    unsigned m = metaD[(size_t)r * JC + t];   // coalesced: transposed layout
    int st = m >> 16, c = m & 0xFFFFu;
    segpre[t + 1] = c;
    if (t == 0) segpre[0] = 0;
    if (t < RANGE) indeg[t] = 0;
    __syncthreads();
    // Hillis-Steele inclusive scan over 512 segment counts
    for (int off = 1; off < JC; off <<= 1) {
        int v = (t + 1 > off) ? segpre[t + 1 - off] : 0;
        __syncthreads();
        segpre[t + 1] += v;
        __syncthreads();
    }
    int total = segpre[JC];
    bool ovf = total > CAP;
    // collect my segment into raw + count in-degrees (single global segment read)
    const uint2* p = recs + (size_t)t * chunk + st;
    if (!ovf) {
        int dp = segpre[t];
        for (int k = 0; k < c; k++) {
            uint2 rec = p[k];
            raw[dp + k] = rec;
            atomicAdd(&indeg[rec.x >> 17], 1);
        }
    } else {
        for (int k = 0; k < c; k++) atomicAdd(&indeg[p[k].x >> 17], 1);
    }
    __syncthreads();
    // node-count prefix scan (RANGE = 128)
    if (t < RANGE) pre[t + 1] = indeg[t];
    if (t == 0) pre[0] = 0;
    __syncthreads();
    for (int off = 1; off < RANGE; off <<= 1) {
        int v = 0;
        if (t < RANGE) { int idx = t + 1; if (idx > off) v = pre[idx - off]; }
        __syncthreads();
        if (t < RANGE) pre[t + 1] += v;
        __syncthreads();
    }
    if (t < RANGE) indeg[t] = pre[t];   // reuse indeg as sort cursors
    __syncthreads();
    // sort raw -> srec by node
    if (!ovf) {
        for (int i = t; i < total; i += 512) {
            uint2 rec = raw[i];
            int dl = rec.x >> 17;
            int pos = atomicAdd(&indeg[dl], 1);
            srec[pos] = make_uint2(rec.x & 0x1FFFFu, rec.y);
        }
    }
    __syncthreads();
    // gather: 4 lanes per node, 16B bf16 chunks, 4x unrolled register accumulation
    int node = t >> 2;
    int cch = t & 3;
    if (node >= lim) return;
    int p0i = pre[node];
    int cnt = pre[node + 1] - p0i;
    float a0 = 0.f, a1 = 0.f, a2 = 0.f, a3 = 0.f, a4 = 0.f, a5 = 0.f, a6 = 0.f, a7 = 0.f;
    if (!ovf) {
        const uint2* sp = srec + p0i;
        int i = 0;
        for (; i + 4 <= cnt; i += 4) {
            uint2 q0 = sp[i], q1 = sp[i + 1], q2 = sp[i + 2], q3 = sp[i + 3];
            uint4 b0 = ((const uint4*)(featb + (size_t)q0.x * D))[cch];
            uint4 b1 = ((const uint4*)(featb + (size_t)q1.x * D))[cch];
            uint4 b2 = ((const uint4*)(featb + (size_t)q2.x * D))[cch];
            uint4 b3 = ((const uint4*)(featb + (size_t)q3.x * D))[cch];
            float w0 = __uint_as_float(q0.y), w1 = __uint_as_float(q1.y);
            float w2 = __uint_as_float(q2.y), w3 = __uint_as_float(q3.y);
            a0 += __uint_as_float(b0.x << 16) * w0 + __uint_as_float(b1.x << 16) * w1
                + __uint_as_float(b2.x << 16) * w2 + __uint_as_float(b3.x << 16) * w3;
            a1 += __uint_as_float(b0.x & 0xFFFF0000u) * w0 + __uint_as_float(b1.x & 0xFFFF0000u) * w1
                + __uint_as_float(b2.x & 0xFFFF0000u) * w2 + __uint_as_float(b3.x & 0xFFFF0000u) * w3;
            a2 += __uint_as_float(b0.y << 16) * w0 + __uint_as_float(b1.y << 16) * w1
                + __uint_as_float(b2.y << 16) * w2 + __uint_as_float(b3.y << 16) * w3;
            a3 += __uint_as_float(b0.y & 0xFFFF0000u) * w0 + __uint_as_float(b1.y & 0xFFFF0000u) * w1
                + __uint_as_float(b2.y & 0xFFFF0000u) * w2 + __uint_as_float(b3.y & 0xFFFF0000u) * w3;
            a4 += __uint_as_float(b0.z << 16) * w0 + __uint_as_float(b1.z << 16) * w1
                + __uint_as_float(b2.z << 16) * w2 + __uint_as_float(b3.z << 16) * w3;
            a5 += __uint_as_float(b0.z & 0xFFFF0000u) * w0 + __uint_as_float(b1.z & 0xFFFF0000u) * w1
                + __uint_as_float(b2.z & 0xFFFF0000u) * w2 + __uint_as_float(b3.z & 0xFFFF0000u) * w3;
            a6 += __uint_as_float(b0.w << 16) * w0 + __uint_as_float(b1.w << 16) * w1
                + __uint_as_float(b2.w << 16) * w2 + __uint_as_float(b3.w << 16) * w3;
            a7 += __uint_as_float(b0.w & 0xFFFF0000u) * w0 + __uint_as_float(b1.w & 0xFFFF0000u) * w1
                + __uint_as_float(b2.w & 0xFFFF0000u) * w2 + __uint_as_float(b3.w & 0xFFFF0000u) * w3;
        }
        for (; i < cnt; i++) {
            uint2 q = sp[i];
            uint4 b = ((const uint4*)(featb + (size_t)q.x * D))[cch];
            float w = __uint_as_float(q.y);
            a0 += __uint_as_float(b.x << 16) * w;
            a1 += __uint_as_float(b.x & 0xFFFF0000u) * w;
            a2 += __uint_as_float(b.y << 16) * w;
            a3 += __uint_as_float(b.y & 0xFFFF0000u) * w;
            a4 += __uint_as_float(b.z << 16) * w;
            a5 += __uint_as_float(b.z & 0xFFFF0000u) * w;
            a6 += __uint_as_float(b.w << 16) * w;
            a7 += __uint_as_float(b.w & 0xFFFF0000u) * w;
        }
    } else {
        // overflow fallback: direct scan of all segments (statistically never taken)
        for (int j = 0; j < JC; j++) {
            unsigned mm = metaD[(size_t)r * JC + j];
            const uint2* pp = recs + (size_t)j * chunk + (mm >> 16);
            int cc = mm & 0xFFFFu;
            for (int k = 0; k < cc; k++) {
                uint2 rec = pp[k];
                if ((int)(rec.x >> 17) == node) {
                    uint4 b = ((const uint4*)(featb + (size_t)(rec.x & 0x1FFFFu) * D))[cch];
                    float w = __uint_as_float(rec.y);
                    a0 += __uint_as_float(b.x << 16) * w;
                    a1 += __uint_as_float(b.x & 0xFFFF0000u) * w;
                    a2 += __uint_as_float(b.y << 16) * w;
                    a3 += __uint_as_float(b.y & 0xFFFF0000u) * w;
                    a4 += __uint_as_float(b.z << 16) * w;
                    a5 += __uint_as_float(b.z & 0xFFFF0000u) * w;
                    a6 += __uint_as_float(b.w << 16) * w;
                    a7 += __uint_as_float(b.w & 0xFFFF0000u) * w;
                }
            }
        }
    }
    float dn = rsqrtf((float)max(cnt, 1));
    const float4* fr = (const float4*)(feat + (size_t)(base + node) * D);
    float4 fA = fr[cch * 2];
    float4 fB = fr[cch * 2 + 1];
    float v = fabsf(fA.x - a0 * dn) + fabsf(fA.y - a1 * dn) +
              fabsf(fA.z - a2 * dn) + fabsf(fA.w - a3 * dn) +
              fabsf(fB.x - a4 * dn) + fabsf(fB.y - a5 * dn) +
              fabsf(fB.z - a6 * dn) + fabsf(fB.w - a7 * dn);
    v += __shfl_xor(v, 1, 4);
    v += __shfl_xor(v, 2, 4);
    if (cch == 0) out[base + node] = v;
}

extern "C" void kernel_launch(void* const* d_in, const int* in_sizes, int n_in,
                              void* d_out, int out_size, void* d_ws, size_t ws_size,
                              hipStream_t stream) {
    const float* feat   = (const float*)d_in[0];
    const float* e_feat = (const float*)d_in[1];
    const int*   src    = (const int*)d_in[2];
    const int*   dst    = (const int*)d_in[3];
    const int E = in_sizes[2];
    const int n = in_sizes[0] / D;
    float* out = (float*)d_out;

    const int R = (n + RANGE - 1) / RANGE;                 // 782
    const int chunk  = (((E + JC  - 1) / JC ) + 1) & ~1;   // 3126  (even, <= CHUNKMAX)
    const int chunkS = (((E + SJC - 1) / SJC) + 1) & ~1;   // 12500 (even, <= SCHUNKMAX, < 65536)

    // ws layout (16B-aligned):
    //   recs[JC*chunk] uint2 | metaD[R*JC] uint | srcs[SJC*chunkS] uint |
    //   metaS[SJC*R] uint | featb[n*D] ushort                     (~27.6 MB)
    char* p = (char*)d_ws;
    uint2* recs     = (uint2*)p;    p += ((size_t)JC * chunk * 8 + 15) & ~(size_t)15;
    unsigned* metaD = (unsigned*)p; p += ((size_t)R * JC * 4 + 15) & ~(size_t)15;
    unsigned* srcs  = (unsigned*)p; p += ((size_t)SJC * chunkS * 4 + 15) & ~(size_t)15;
    unsigned* metaS = (unsigned*)p; p += ((size_t)SJC * R * 4 + 15) & ~(size_t)15;
    unsigned short* featb = (unsigned short*)p;

    sort_src<<<SJC, 512, 0, stream>>>(src, srcs, metaS, E, R, chunkS);

    sort_chunks<<<JC, 512, 0, stream>>>(src, dst, e_feat, recs, metaD, E, R, chunk);

    srcnorm_convert<<<R, 512, 0, stream>>>(srcs, metaS, feat, featb, n, R, chunkS);

    gather_kernel<<<R, 512, 0, stream>>>(feat, featb, recs, metaD, out, n, R, chunk);
}

// Round 4
// 139.273 us; speedup vs baseline: 1.3622x; 1.0450x over previous
//
#include <hip/hip_runtime.h>

#define D 32
#define RANGE 128        // nodes per range; R = ceil(n/RANGE) = 782
#define RMAX 800         // range-counter capacity (>= R)
#define JC 512           // dst edge chunks == blockDim of gather's segment loop
#define CHUNKMAX 3200    // LDS record capacity per dst sort block (chunk = 3126)
#define CAP 2304         // gather LDS record capacity per range (mean 2048, +5.7 sigma)
#define SJC 256          // src edge chunks (chunkS = 6250 -> 32B avg cell in consumer)
#define SCHUNKMAX 6400   // id capacity of src arena region (25600 B)

// ---- wave-shfl block scan: inclusive scan of one value per thread (512 threads,
// 8 waves). 1 internal barrier (vs 18-20 for Hillis-Steele over LDS).
// wp[8] holds per-wave totals after the call (valid until overwritten).
__device__ __forceinline__ int scan512(int x, int* wp, int t) {
    int lane = t & 63, w = t >> 6;
    #pragma unroll
    for (int d = 1; d < 64; d <<= 1) {
        int y = __shfl_up(x, d, 64);
        if (lane >= d) x += y;
    }
    if (lane == 63) wp[w] = x;
    __syncthreads();
    int off = 0;
    #pragma unroll
    for (int i = 0; i < 7; i++) if (i < w) off += wp[i];
    return x + off;
}

// ---- K1: fused independent sorts. Blocks [0,JC) counting-sort DST records by
// range (chunk-contiguous recs + transposed metaD[r][j]); blocks [JC,JC+SJC)
// counting-sort SRC ids coarsely (chunk-contiguous srcs + metaS[j][r]).
// Fusion removes sort_src's serial half-idle-GPU phase: all 768 blocks fit
// co-resident (4 blocks/CU with the 32KB arena).
__global__ __launch_bounds__(512) void fused_sort(
        const int* __restrict__ src, const int* __restrict__ dst,
        const float* __restrict__ ef,
        uint2* __restrict__ recs, unsigned* __restrict__ metaD,
        unsigned* __restrict__ srcs, unsigned* __restrict__ metaS,
        int E, int R, int chunk, int chunkS) {
    __shared__ __align__(16) char arena[32000];   // sd[3200]u2 | cnt[800] | cur[800]
    __shared__ int wp[8];
    int t = threadIdx.x;
    int* cnt = (int*)(arena + 25600);
    int* cur = (int*)(arena + 28800);

    if (blockIdx.x < JC) {
        // ---------------- dst-record sort ----------------
        int j = blockIdx.x;
        uint2* sd = (uint2*)arena;               // 25600 B
        int e0 = j * chunk, e1 = min(E, e0 + chunk), cntE = e1 - e0;
        for (int i = t; i < RMAX; i += 512) cnt[i] = 0;
        __syncthreads();
        for (int e = e0 + 2 * t; e < e1; e += 1024) {
            if (e + 1 < e1) {
                int2 d2 = *(const int2*)(dst + e);
                atomicAdd(&cnt[d2.x >> 7], 1);
                atomicAdd(&cnt[d2.y >> 7], 1);
            } else {
                atomicAdd(&cnt[dst[e] >> 7], 1);
            }
        }
        __syncthreads();
        // 800-entry exclusive scan = two 512-wide shfl scans
        int v0 = cnt[t];
        int incl0 = scan512(v0, wp, t);
        int tot0 = wp[0] + wp[1] + wp[2] + wp[3] + wp[4] + wp[5] + wp[6] + wp[7];
        __syncthreads();
        int i1 = t + 512;
        int v1 = (i1 < RMAX) ? cnt[i1] : 0;
        int incl1 = scan512(v1, wp, t);
        cur[t] = incl0 - v0;
        if (i1 < RMAX) cur[i1] = tot0 + incl1 - v1;
        __syncthreads();
        // place into LDS sorted by range
        for (int e = e0 + t; e < e1; e += 512) {
            int s = src[e], d = dst[e];
            float w = (s == d) ? 0.0f : ef[e];
            int pos = atomicAdd(&cur[d >> 7], 1);
            sd[pos] = make_uint2((unsigned)s | ((unsigned)(d & (RANGE - 1)) << 17),
                                 __float_as_uint(w));
        }
        __syncthreads();
        size_t baseE = (size_t)j * chunk;
        for (int i = t; i < cntE; i += 512) recs[baseE + i] = sd[i];
        for (int i = t; i < R; i += 512)
            metaD[(size_t)i * JC + j] =
                ((unsigned)(cur[i] - cnt[i]) << 16) | (unsigned)cnt[i];
    } else {
        // ---------------- coarse src-id sort ----------------
        int j = blockIdx.x - JC;
        unsigned* ids = (unsigned*)arena;        // up to 6400 ids
        int e0 = j * chunkS, e1 = min(E, e0 + chunkS), cntE = e1 - e0;
        for (int i = t; i < RMAX; i += 512) cnt[i] = 0;
        __syncthreads();
        for (int e = e0 + 2 * t; e < e1; e += 1024) {
            if (e + 1 < e1) {
                int2 s2 = *(const int2*)(src + e);
                atomicAdd(&cnt[s2.x >> 7], 1);
                atomicAdd(&cnt[s2.y >> 7], 1);
            } else {
                atomicAdd(&cnt[src[e] >> 7], 1);
            }
        }
        __syncthreads();
        int v0 = cnt[t];
        int incl0 = scan512(v0, wp, t);
        int tot0 = wp[0] + wp[1] + wp[2] + wp[3] + wp[4] + wp[5] + wp[6] + wp[7];
        __syncthreads();
        int i1 = t + 512;
        int v1 = (i1 < RMAX) ? cnt[i1] : 0;
        int incl1 = scan512(v1, wp, t);
        cur[t] = incl0 - v0;
        if (i1 < RMAX) cur[i1] = tot0 + incl1 - v1;
        __syncthreads();
        for (int e = e0 + t; e < e1; e += 512) {
            unsigned s = (unsigned)src[e];
            int pos = atomicAdd(&cur[s >> 7], 1);
            ids[pos] = s;
        }
        __syncthreads();
        size_t baseE = (size_t)j * chunkS;
        for (int i = t; i < cntE; i += 512) srcs[baseE + i] = ids[i];
        // meta [j][r]: start,count <= 6250 fit 16 bits
        for (int i = t; i < R; i += 512)
            metaS[(size_t)j * R + i] =
                ((unsigned)(cur[i] - cnt[i]) << 16) | (unsigned)cnt[i];
    }
}

// ---- K2: per-range out-degree count from coarse src segments (32B cells,
// 2 threads/segment) + pre-scaled bf16 convert. ----
__device__ __forceinline__ unsigned short f2bf(float x) {
    unsigned u = __float_as_uint(x);
    u += 0x7FFFu + ((u >> 16) & 1u);
    return (unsigned short)(u >> 16);
}

__global__ __launch_bounds__(512) void srcnorm_convert(
        const unsigned* __restrict__ srcs, const unsigned* __restrict__ metaS,
        const float* __restrict__ feat, unsigned short* __restrict__ featb,
        int n, int R, int chunkS) {
    __shared__ int cnt[RANGE];
    __shared__ unsigned meta[SJC];
    int r = blockIdx.x, t = threadIdx.x;
    int base = r * RANGE, lim = min(n - base, RANGE);
    if (t < RANGE) cnt[t] = 0;
    if (t < SJC) meta[t] = metaS[(size_t)t * R + r];
    __syncthreads();
    // 2 threads per segment
    int seg = t >> 1, sub = t & 1;
    {
        unsigned m = meta[seg];
        int st = m >> 16, c = m & 0xFFFFu;
        const unsigned* p = srcs + (size_t)seg * chunkS + st;
        for (int k = sub; k < c; k += 2)
            atomicAdd(&cnt[p[k] - (unsigned)base], 1);
    }
    __syncthreads();
    int total4 = lim * 8;   // 8 float4 chunks per row
    for (int i = t; i < total4; i += 512) {
        int row = i >> 3;
        float sn = rsqrtf((float)max(cnt[row], 1));
        float4 f = ((const float4*)(feat + (size_t)(base + row) * D))[i & 7];
        ushort4 u;
        u.x = f2bf(f.x * sn); u.y = f2bf(f.y * sn);
        u.z = f2bf(f.z * sn); u.w = f2bf(f.w * sn);
        ((ushort4*)(featb + (size_t)(base + row) * D))[i & 7] = u;
    }
}

// ---- K3: per-range segment collect -> LDS node-sort -> register gather + output.
// Scans converted to wave-shfl (removes segpre array + ~30 barriers).
__global__ __launch_bounds__(512) void gather_kernel(
        const float* __restrict__ feat, const unsigned short* __restrict__ featb,
        const uint2* __restrict__ recs, const unsigned* __restrict__ metaD,
        float* __restrict__ out, int n, int R, int chunk) {
    __shared__ uint2 raw[CAP];           // 18 KB segment-appended records
    __shared__ uint2 srec[CAP];          // 18 KB node-sorted records
    __shared__ int indeg[RANGE];         // counts, then reused as sort cursors
    __shared__ int pre[RANGE + 1];
    __shared__ int wp[8];
    int r = blockIdx.x, t = threadIdx.x;
    int base = r * RANGE, lim = min(n - base, RANGE);
    unsigned m = metaD[(size_t)r * JC + t];   // coalesced: transposed layout
    int st = m >> 16, c = m & 0xFFFFu;
    if (t < RANGE) indeg[t] = 0;
    // segment-count scan (wave-shfl; internal barrier also covers indeg zeroing)
    int incl = scan512(c, wp, t);
    int dp = incl - c;
    int total = wp[0] + wp[1] + wp[2] + wp[3] + wp[4] + wp[5] + wp[6] + wp[7];
    bool ovf = total > CAP;
    // collect my segment into raw + count in-degrees (single global segment read)
    const uint2* p = recs + (size_t)t * chunk + st;
    if (!ovf) {
        for (int k = 0; k < c; k++) {
            uint2 rec = p[k];
            raw[dp + k] = rec;
            atomicAdd(&indeg[rec.x >> 17], 1);
        }
    } else {
        for (int k = 0; k < c; k++) atomicAdd(&indeg[p[k].x >> 17], 1);
    }
    __syncthreads();
    // node-count prefix scan (128 live elements; zeros beyond don't affect them)
    int vv = (t < RANGE) ? indeg[t] : 0;
    int incl2 = scan512(vv, wp, t);
    if (t < RANGE) pre[t + 1] = incl2;
    if (t == 0) pre[0] = 0;
    __syncthreads();
    if (t < RANGE) indeg[t] = pre[t];   // reuse indeg as sort cursors
    __syncthreads();
    // sort raw -> srec by node
    if (!ovf) {
        for (int i = t; i < total; i += 512) {
            uint2 rec = raw[i];
            int dl = rec.x >> 17;
            int pos = atomicAdd(&indeg[dl], 1);
            srec[pos] = make_uint2(rec.x & 0x1FFFFu, rec.y);
        }
    }
    __syncthreads();
    // gather: 4 lanes per node, 16B bf16 chunks, 4x unrolled register accumulation
    int node = t >> 2;
    int cch = t & 3;
    if (node >= lim) return;
    int p0i = pre[node];
    int cnt = pre[node + 1] - p0i;
    float a0 = 0.f, a1 = 0.f, a2 = 0.f, a3 = 0.f, a4 = 0.f, a5 = 0.f, a6 = 0.f, a7 = 0.f;
    if (!ovf) {
        const uint2* sp = srec + p0i;
        int i = 0;
        for (; i + 4 <= cnt; i += 4) {
            uint2 q0 = sp[i], q1 = sp[i + 1], q2 = sp[i + 2], q3 = sp[i + 3];
            uint4 b0 = ((const uint4*)(featb + (size_t)q0.x * D))[cch];
            uint4 b1 = ((const uint4*)(featb + (size_t)q1.x * D))[cch];
            uint4 b2 = ((const uint4*)(featb + (size_t)q2.x * D))[cch];
            uint4 b3 = ((const uint4*)(featb + (size_t)q3.x * D))[cch];
            float w0 = __uint_as_float(q0.y), w1 = __uint_as_float(q1.y);
            float w2 = __uint_as_float(q2.y), w3 = __uint_as_float(q3.y);
            a0 += __uint_as_float(b0.x << 16) * w0 + __uint_as_float(b1.x << 16) * w1
                + __uint_as_float(b2.x << 16) * w2 + __uint_as_float(b3.x << 16) * w3;
            a1 += __uint_as_float(b0.x & 0xFFFF0000u) * w0 + __uint_as_float(b1.x & 0xFFFF0000u) * w1
                + __uint_as_float(b2.x & 0xFFFF0000u) * w2 + __uint_as_float(b3.x & 0xFFFF0000u) * w3;
            a2 += __uint_as_float(b0.y << 16) * w0 + __uint_as_float(b1.y << 16) * w1
                + __uint_as_float(b2.y << 16) * w2 + __uint_as_float(b3.y << 16) * w3;
            a3 += __uint_as_float(b0.y & 0xFFFF0000u) * w0 + __uint_as_float(b1.y & 0xFFFF0000u) * w1
                + __uint_as_float(b2.y & 0xFFFF0000u) * w2 + __uint_as_float(b3.y & 0xFFFF0000u) * w3;
            a4 += __uint_as_float(b0.z << 16) * w0 + __uint_as_float(b1.z << 16) * w1
                + __uint_as_float(b2.z << 16) * w2 + __uint_as_float(b3.z << 16) * w3;
            a5 += __uint_as_float(b0.z & 0xFFFF0000u) * w0 + __uint_as_float(b1.z & 0xFFFF0000u) * w1
                + __uint_as_float(b2.z & 0xFFFF0000u) * w2 + __uint_as_float(b3.z & 0xFFFF0000u) * w3;
            a6 += __uint_as_float(b0.w << 16) * w0 + __uint_as_float(b1.w << 16) * w1
                + __uint_as_float(b2.w << 16) * w2 + __uint_as_float(b3.w << 16) * w3;
            a7 += __uint_as_float(b0.w & 0xFFFF0000u) * w0 + __uint_as_float(b1.w & 0xFFFF0000u) * w1
                + __uint_as_float(b2.w & 0xFFFF0000u) * w2 + __uint_as_float(b3.w & 0xFFFF0000u) * w3;
        }
        for (; i < cnt; i++) {
            uint2 q = sp[i];
            uint4 b = ((const uint4*)(featb + (size_t)q.x * D))[cch];
            float w = __uint_as_float(q.y);
            a0 += __uint_as_float(b.x << 16) * w;
            a1 += __uint_as_float(b.x & 0xFFFF0000u) * w;
            a2 += __uint_as_float(b.y << 16) * w;
            a3 += __uint_as_float(b.y & 0xFFFF0000u) * w;
            a4 += __uint_as_float(b.z << 16) * w;
            a5 += __uint_as_float(b.z & 0xFFFF0000u) * w;
            a6 += __uint_as_float(b.w << 16) * w;
            a7 += __uint_as_float(b.w & 0xFFFF0000u) * w;
        }
    } else {
        // overflow fallback: direct scan of all segments (statistically never taken)
        for (int j = 0; j < JC; j++) {
            unsigned mm = metaD[(size_t)r * JC + j];
            const uint2* pp = recs + (size_t)j * chunk + (mm >> 16);
            int cc = mm & 0xFFFFu;
            for (int k = 0; k < cc; k++) {
                uint2 rec = pp[k];
                if ((int)(rec.x >> 17) == node) {
                    uint4 b = ((const uint4*)(featb + (size_t)(rec.x & 0x1FFFFu) * D))[cch];
                    float w = __uint_as_float(rec.y);
                    a0 += __uint_as_float(b.x << 16) * w;
                    a1 += __uint_as_float(b.x & 0xFFFF0000u) * w;
                    a2 += __uint_as_float(b.y << 16) * w;
                    a3 += __uint_as_float(b.y & 0xFFFF0000u) * w;
                    a4 += __uint_as_float(b.z << 16) * w;
                    a5 += __uint_as_float(b.z & 0xFFFF0000u) * w;
                    a6 += __uint_as_float(b.w << 16) * w;
                    a7 += __uint_as_float(b.w & 0xFFFF0000u) * w;
                }
            }
        }
    }
    float dn = rsqrtf((float)max(cnt, 1));
    const float4* fr = (const float4*)(feat + (size_t)(base + node) * D);
    float4 fA = fr[cch * 2];
    float4 fB = fr[cch * 2 + 1];
    float v = fabsf(fA.x - a0 * dn) + fabsf(fA.y - a1 * dn) +
              fabsf(fA.z - a2 * dn) + fabsf(fA.w - a3 * dn) +
              fabsf(fB.x - a4 * dn) + fabsf(fB.y - a5 * dn) +
              fabsf(fB.z - a6 * dn) + fabsf(fB.w - a7 * dn);
    v += __shfl_xor(v, 1, 4);
    v += __shfl_xor(v, 2, 4);
    if (cch == 0) out[base + node] = v;
}

extern "C" void kernel_launch(void* const* d_in, const int* in_sizes, int n_in,
                              void* d_out, int out_size, void* d_ws, size_t ws_size,
                              hipStream_t stream) {
    const float* feat   = (const float*)d_in[0];
    const float* e_feat = (const float*)d_in[1];
    const int*   src    = (const int*)d_in[2];
    const int*   dst    = (const int*)d_in[3];
    const int E = in_sizes[2];
    const int n = in_sizes[0] / D;
    float* out = (float*)d_out;

    const int R = (n + RANGE - 1) / RANGE;                 // 782
    const int chunk  = (((E + JC  - 1) / JC ) + 1) & ~1;   // 3126 (even, <= CHUNKMAX)
    const int chunkS = (((E + SJC - 1) / SJC) + 1) & ~1;   // 6250 (even, <= SCHUNKMAX)

    // ws layout (16B-aligned):
    //   recs[JC*chunk] uint2 | metaD[R*JC] uint | srcs[SJC*chunkS] uint |
    //   metaS[SJC*R] uint | featb[n*D] ushort
    char* p = (char*)d_ws;
    uint2* recs     = (uint2*)p;    p += ((size_t)JC * chunk * 8 + 15) & ~(size_t)15;
    unsigned* metaD = (unsigned*)p; p += ((size_t)R * JC * 4 + 15) & ~(size_t)15;
    unsigned* srcs  = (unsigned*)p; p += ((size_t)SJC * chunkS * 4 + 15) & ~(size_t)15;
    unsigned* metaS = (unsigned*)p; p += ((size_t)SJC * R * 4 + 15) & ~(size_t)15;
    unsigned short* featb = (unsigned short*)p;

    fused_sort<<<JC + SJC, 512, 0, stream>>>(src, dst, e_feat, recs, metaD,
                                             srcs, metaS, E, R, chunk, chunkS);

    srcnorm_convert<<<R, 512, 0, stream>>>(srcs, metaS, feat, featb, n, R, chunkS);

    gather_kernel<<<R, 512, 0, stream>>>(feat, featb, recs, metaD, out, n, R, chunk);
}